// Round 14
// baseline (273.406 us; speedup 1.0000x reference)
//
#include <hip/hip_runtime.h>

typedef unsigned short u16;
typedef unsigned int   u32;
typedef float  f32x16 __attribute__((ext_vector_type(16)));
typedef __bf16 bf16x8 __attribute__((ext_vector_type(8)));

#define B_N   8
#define T_N   1500
#define D_N   512
#define K_N   4096
#define NTOK  12000
#define STRD  320

// ---- workspace byte offsets (~29.8 MB total) ----
#define X2S_OFF     0u                      // 12000 f
#define C2_OFF      49152u                  // 4096 f
#define FEATP_OFF   65536u                  // 375 f
#define TRIPP_OFF   67584u                  // 375 f
#define STATEP_OFF  69632u                  // 5*4*12000 f
#define SBF_OFF     1048576u                // 375 tiles * 32KB
#define TBF_OFF     (1048576u + 12288000u)
#define CBBF_OFF    (1048576u + 24576000u)  // 4 MB

#define ST_S1  12000                        // stateP ch stride (floats)
#define ST_SQ  48000                        // stateP quantity stride (floats)

// ---- global bf16 layouts, 16B chunks of 8 consecutive k ----
// sbf/tbf: chunk16 = (tt32*32 + ks)*64 + kh*32 + sp  (token=tt32*32+sp, k=ks*16+kh*8+j)
// cbbf: region r = ch*64 + cg*16 + kc (16KB = 8192 u16); within (u16):
//       off = ctg*1024 + ks2*512 + kh*256 + sp*8
//       (code = ch*1024+cg*256+ctg*32+sp, k = kc*32+ks2*16+kh*8+j)
// main A-LDS (32KB): chunk16 = ks*64 + kh*32 + mat*16 + tok4
//       (col = mat*16+tok4: 0..15 student, 16..31 teacher; one MFMA does both)

__device__ __forceinline__ u16 f2bf(float x){
  u32 u = __float_as_uint(x);
  u32 r = (u + 0x7fffu + ((u >> 16) & 1u)) >> 16;   // RNE
  return (u16)r;
}

__device__ __forceinline__ void gl_lds16(const void* g, void* l){
  __builtin_amdgcn_global_load_lds(
      (__attribute__((address_space(1))) void*)(g),
      (__attribute__((address_space(3))) void*)(l),
      16, 0, 0);
}

__device__ __forceinline__ void merge_state(float& m, float& Z, float om, float oZ){
  float nm = fmaxf(m, om);
  Z = Z*__expf(m - nm) + oZ*__expf(om - nm);
  m = nm;
}
__device__ __forceinline__ void merge_stateT(float& m, float& Z, float& A,
                                             float om, float oZ, float oA){
  float nm = fmaxf(m, om);
  float e0 = __expf(m - nm), e1 = __expf(om - nm);
  Z = Z*e0 + oZ*e1; A = A*e0 + oA*e1; m = nm;
}

// ============ prep: blocks 0..374 tokens; 375..406 codebook (green r11) ============
__global__ __launch_bounds__(256) void prep_kernel(
    const float* __restrict__ s, const float* __restrict__ t,
    const float* __restrict__ cb, const int* __restrict__ lengths,
    u16* __restrict__ sbf, u16* __restrict__ tbf, u16* __restrict__ cbbf,
    float* __restrict__ x2s, float* __restrict__ c2,
    float* __restrict__ featP, float* __restrict__ tripP)
{
  const int tid = threadIdx.x;
  const int w = tid >> 6, lane = tid & 63;
  __shared__ float sred[3][32];

  if (blockIdx.x < 375){
    const int tt = blockIdx.x;
    const int t8 = lane >> 3, kpart = lane & 7;
    const int tokL = w*8 + t8;                  // 0..31
    const int n = tt*32 + tokL;
    const int b = n / T_N, tok = n - b*T_N;
    const int nr = ((b+7)&7)*T_N + tok;         // roll(teacher,+1,axis=0)
    const float* srow = s + (size_t)n  * D_N;
    const float* trow = t + (size_t)n  * D_N;
    const float* rrow = t + (size_t)nr * D_N;

    float x2 = 0.f, sd2 = 0.f, nd2 = 0.f;
    uint4 sbq[8], tbq[8];
#pragma unroll
    for (int q = 0; q < 8; ++q){
      const int kl = q*64 + kpart*8;
      float4 a0 = *(const float4*)(srow + kl), a1 = *(const float4*)(srow + kl + 4);
      float4 b0 = *(const float4*)(trow + kl), b1 = *(const float4*)(trow + kl + 4);
      float4 r0 = *(const float4*)(rrow + kl), r1 = *(const float4*)(rrow + kl + 4);
      float sv[8] = {a0.x,a0.y,a0.z,a0.w,a1.x,a1.y,a1.z,a1.w};
      float tv[8] = {b0.x,b0.y,b0.z,b0.w,b1.x,b1.y,b1.z,b1.w};
      float rv[8] = {r0.x,r0.y,r0.z,r0.w,r1.x,r1.y,r1.z,r1.w};
      u16 sb[8], tb[8];
#pragma unroll
      for (int i = 0; i < 8; ++i){
        float d = sv[i] - tv[i]; sd2 += d*d;
        x2 += sv[i]*sv[i];
        float e = sv[i] - rv[i]; nd2 += e*e;
        sb[i] = f2bf(sv[i]); tb[i] = f2bf(tv[i]);
      }
      sbq[q].x = (u32)sb[0] | ((u32)sb[1]<<16); sbq[q].y = (u32)sb[2] | ((u32)sb[3]<<16);
      sbq[q].z = (u32)sb[4] | ((u32)sb[5]<<16); sbq[q].w = (u32)sb[6] | ((u32)sb[7]<<16);
      tbq[q].x = (u32)tb[0] | ((u32)tb[1]<<16); tbq[q].y = (u32)tb[2] | ((u32)tb[3]<<16);
      tbq[q].z = (u32)tb[4] | ((u32)tb[5]<<16); tbq[q].w = (u32)tb[6] | ((u32)tb[7]<<16);
    }
#pragma unroll
    for (int q = 0; q < 8; ++q){
      const int ks = q*4 + (kpart >> 1), kh = kpart & 1;
      const size_t chunk = ((size_t)tt*32 + ks)*64 + kh*32 + tokL;
      ((uint4*)sbf)[chunk] = sbq[q];
      ((uint4*)tbf)[chunk] = tbq[q];
    }
#pragma unroll
    for (int mm = 1; mm < 8; mm <<= 1){
      x2  += __shfl_xor(x2,  mm);
      sd2 += __shfl_xor(sd2, mm);
      nd2 += __shfl_xor(nd2, mm);
    }
    if (kpart == 0){ sred[0][tokL] = x2; sred[1][tokL] = sd2; sred[2][tokL] = nd2; }
    __syncthreads();
    if (tid < 32){
      float X2 = sred[0][tid], SD = sred[1][tid], ND = sred[2][tid];
      int n2 = tt*32 + tid, b2 = n2 / T_N, tk2 = n2 - b2*T_N;
      x2s[n2] = X2;
      int valid = lengths[b2] / STRD; if (valid > T_N) valid = T_N;
      float mf = (tk2 < valid) ? 1.f : 0.f;
      float fp = mf * SD * (1.f/512.f);
      float tp = mf * fmaxf(sqrtf(SD) - sqrtf(ND) + 0.2f, 0.f);
#pragma unroll
      for (int mm = 1; mm < 32; mm <<= 1){ fp += __shfl_xor(fp, mm); tp += __shfl_xor(tp, mm); }
      if (tid == 0){ featP[tt] = fp; tripP[tt] = tp; }
    }
  } else {
    const int idx = blockIdx.x - 375;
    const int ctile = idx*4 + w;                // 0..127
    const int kh = lane >> 5, sp = lane & 31;
    const int ch = ctile >> 5, cg = (ctile >> 3) & 3, ctg = ctile & 7;
    const int code = ctile*32 + sp;
    const float* crow = cb + (size_t)code * D_N;

    float s2 = 0.f;
#pragma unroll
    for (int stp = 0; stp < 32; ++stp){
      const int kc = stp >> 1, ks2 = stp & 1;
      const int k0 = stp*16 + kh*8;
      float4 c0 = *(const float4*)(crow + k0), c1 = *(const float4*)(crow + k0 + 4);
      float cv[8] = {c0.x,c0.y,c0.z,c0.w,c1.x,c1.y,c1.z,c1.w};
      u16 cbv[8];
#pragma unroll
      for (int i = 0; i < 8; ++i){ s2 += cv[i]*cv[i]; cbv[i] = f2bf(cv[i]); }
      uint4 pk;
      pk.x = (u32)cbv[0] | ((u32)cbv[1]<<16); pk.y = (u32)cbv[2] | ((u32)cbv[3]<<16);
      pk.z = (u32)cbv[4] | ((u32)cbv[5]<<16); pk.w = (u32)cbv[6] | ((u32)cbv[7]<<16);
      const size_t off = ((size_t)(ch*64 + cg*16 + kc))*8192 + ctg*1024 + ks2*512 + lane*8;
      *(uint4*)(cbbf + off) = pk;
    }
    s2 += __shfl_xor(s2, 32);
    if (lane < 32) c2[ctile*32 + lane] = s2;
  }
}

// ============ main: 256 thr, 16 tokens x {s,t} in 32 MFMA cols, 32KB LDS ============
// grid 3000 = 750 token-16-tiles x 4 code-quarters. 64 chunks of 256 codes x 32 k.
// One MFMA computes s AND t logits (cols 0..15 = s, 16..31 = t). 4 blocks/CU.
__global__ __launch_bounds__(256, 4) void main_kl_kernel(
    const u16* __restrict__ sbf, const u16* __restrict__ tbf,
    const u16* __restrict__ cbbf, const float* __restrict__ c2,
    float* __restrict__ stateP)
{
  __shared__ u16 Ab[16384];                     // 32 KB interleaved s/t A-tile

  const int tid = threadIdx.x;
  const int w = tid >> 6, lane = tid & 63;
  const int kh = lane >> 5;
  const int blk = blockIdx.x;
  const int tt16 = blk % 750, ch = blk / 750;
  const int tt32 = tt16 >> 1, half = tt16 & 1;

  const u16* cbB = cbbf + (size_t)ch * 524288;  // 64 regions x 8192 u16

  // ---- stage A once: per-lane src (s or t by lane's mat bit), uniform+lane*16 dest ----
  {
    const int mat  = (lane >> 4) & 1;
    const int tok4 = lane & 15;
    const u16* abase = mat ? tbf : sbf;
    const size_t srcb = (size_t)(tt32*32)*64 + kh*32 + half*16 + tok4;   // + ks*64
#pragma unroll
    for (int r = 0; r < 8; ++r){
      const int ks = r*4 + w;
      gl_lds16(abase + (srcb + (size_t)ks*64)*8, &Ab[ks*512 + lane*8]);
    }
  }

  // B frags chunk 0 (region 0) — identical shape to green r11
  bf16x8 b00, b01, b10, b11;                    // [ct][ks2]
  {
    const u16* rg = cbB;
    b00 = *(const bf16x8*)(rg + (w*2+0)*1024 +       lane*8);
    b01 = *(const bf16x8*)(rg + (w*2+0)*1024 + 512 + lane*8);
    b10 = *(const bf16x8*)(rg + (w*2+1)*1024 +       lane*8);
    b11 = *(const bf16x8*)(rg + (w*2+1)*1024 + 512 + lane*8);
  }

  __syncthreads();                              // A staged (the ONLY pre-loop barrier)

  float mL = -3e38f, zL = 0.f, aL = 0.f;        // per-lane state: (m,z) + a (t-lanes)
  f32x16 a0, a1;                                // ctg = 2w, 2w+1

  for (int c = 0; c < 64; ++c){
    const int kc = c & 15;
    if (kc == 0){
#pragma unroll
      for (int i = 0; i < 16; ++i){ a0[i] = 0.f; a1[i] = 0.f; }
    }
    // 1-deep B prefetch (fine-grained vmcnt, no barrier)
    bf16x8 n00 = b00, n01 = b01, n10 = b10, n11 = b11;
    if (c < 63){
      const u16* rg = cbB + (size_t)(c+1)*8192;
      n00 = *(const bf16x8*)(rg + (w*2+0)*1024 +       lane*8);
      n01 = *(const bf16x8*)(rg + (w*2+0)*1024 + 512 + lane*8);
      n10 = *(const bf16x8*)(rg + (w*2+1)*1024 +       lane*8);
      n11 = *(const bf16x8*)(rg + (w*2+1)*1024 + 512 + lane*8);
    }

    // A frags from LDS (2 per chunk — s/t folded into columns)
    const u16* ap = &Ab[kc*1024 + lane*8];
    bf16x8 as0 = *(const bf16x8*)(ap);
    bf16x8 as1 = *(const bf16x8*)(ap + 512);

    a0 = __builtin_amdgcn_mfma_f32_32x32x16_bf16(b00, as0, a0, 0, 0, 0);
    a1 = __builtin_amdgcn_mfma_f32_32x32x16_bf16(b10, as0, a1, 0, 0, 0);
    a0 = __builtin_amdgcn_mfma_f32_32x32x16_bf16(b01, as1, a0, 0, 0, 0);
    a1 = __builtin_amdgcn_mfma_f32_32x32x16_bf16(b11, as1, a1, 0, 0, 0);
    b00 = n00; b01 = n01; b10 = n10; b11 = n11;

    if (kc == 15){
      const int cg = c >> 4;
#pragma unroll
      for (int ct = 0; ct < 2; ++ct){
        const f32x16& v = ct ? a1 : a0;
        const int ctg = w*2 + ct;
        const float* c2b = c2 + ch*1024 + cg*256 + ctg*32 + kh*4;
        float4 g0 = *(const float4*)(c2b);
        float4 g1 = *(const float4*)(c2b + 8);
        float4 g2 = *(const float4*)(c2b + 16);
        float4 g3 = *(const float4*)(c2b + 24);
        float c2v[16] = {g0.x,g0.y,g0.z,g0.w, g1.x,g1.y,g1.z,g1.w,
                         g2.x,g2.y,g2.z,g2.w, g3.x,g3.y,g3.z,g3.w};
        // pass 1: tile max of this lane's logits
        float mloc = -3e38f;
#pragma unroll
        for (int i = 0; i < 16; ++i) mloc = fmaxf(mloc, 2.0f*v[i] - c2v[i]);
        float nm = fmaxf(mL, mloc);
        float e0 = __expf(mL - nm);
        zL *= e0; aL *= e0;
        // pass 2: recompute; partner logit (other mat, same token+code) via xor-16
#pragma unroll
        for (int i = 0; i < 16; ++i){
          float lv = 2.0f*v[i] - c2v[i];
          float ov = __shfl_xor(lv, 16);
          float e = __expf(lv - nm);
          zL += e; aL += e*(lv - ov);
        }
        mL = nm;
      }
    }
  }

  // merge the two kh halves (xor 32: same (mat,token), disjoint code rows)
  {
    float om = __shfl_xor(mL, 32), oz = __shfl_xor(zL, 32), oa = __shfl_xor(aL, 32);
    merge_stateT(mL, zL, aL, om, oz, oa);
  }
  __syncthreads();                              // Ab dead; reuse as merge buffer
  float* wst = (float*)&Ab[0];                  // [4][32][3] = 1.5 KB
  if (lane < 32){
    float* pw = wst + (w*32 + lane)*3;
    pw[0] = mL; pw[1] = zL; pw[2] = aL;
  }
  __syncthreads();
  if (tid < 32){
    const float* p0 = wst + tid*3;
    float m = p0[0], z = p0[1], a = p0[2];
#pragma unroll
    for (int ww = 1; ww < 4; ++ww){
      const float* pw = wst + (ww*32 + tid)*3;
      merge_stateT(m, z, a, pw[0], pw[1], pw[2]);
    }
    const int mat = tid >> 4, tok4 = tid & 15;
    const int n = tt16*16 + tok4;
    if (mat == 0){
      stateP[0*ST_SQ + ch*ST_S1 + n] = m;
      stateP[1*ST_SQ + ch*ST_S1 + n] = z;
    } else {
      stateP[2*ST_SQ + ch*ST_S1 + n] = m;
      stateP[3*ST_SQ + ch*ST_S1 + n] = z;
      stateP[4*ST_SQ + ch*ST_S1 + n] = a;
    }
  }
}

// ============ tail: merge 4 code-quarters per token; KL/min-dist; reduce ============
__global__ __launch_bounds__(1024) void tail_kernel(
    const float* __restrict__ stateP, const float* __restrict__ x2s,
    const float* __restrict__ featP, const float* __restrict__ tripP,
    const int* __restrict__ lengths, float* __restrict__ out)
{
  const int tid = threadIdx.x;
  double kl_s = 0.0, md_s = 0.0, f = 0.0, tr = 0.0;
  for (int n = tid; n < NTOK; n += 1024){
    float m_s = stateP[0*ST_SQ + n], z_s = stateP[1*ST_SQ + n];
    float m_t = stateP[2*ST_SQ + n], z_t = stateP[3*ST_SQ + n], a = stateP[4*ST_SQ + n];
#pragma unroll
    for (int chh = 1; chh < 4; ++chh){
      merge_state(m_s, z_s, stateP[0*ST_SQ + chh*ST_S1 + n], stateP[1*ST_SQ + chh*ST_S1 + n]);
      merge_stateT(m_t, z_t, a, stateP[2*ST_SQ + chh*ST_S1 + n],
                   stateP[3*ST_SQ + chh*ST_S1 + n], stateP[4*ST_SQ + chh*ST_S1 + n]);
    }
    float klv = a / z_t - (m_t + __logf(z_t)) + (m_s + __logf(z_s));
    int b = n / T_N, tk = n - b*T_N;
    int valid = lengths[b] / STRD; if (valid > T_N) valid = T_N;
    if (tk < valid) kl_s += (double)klv;
    md_s += (double)fmaxf(x2s[n] - m_s, 0.f);
  }
  for (int i = tid; i < 375; i += 1024){ f += (double)featP[i]; tr += (double)tripP[i]; }
#pragma unroll
  for (int mm = 1; mm < 64; mm <<= 1){
    kl_s += __shfl_xor(kl_s, mm); md_s += __shfl_xor(md_s, mm);
    f    += __shfl_xor(f,    mm); tr   += __shfl_xor(tr,   mm);
  }
  __shared__ double red[16][4];
  const int w = tid >> 6, lane = tid & 63;
  if (lane == 0){ red[w][0]=kl_s; red[w][1]=md_s; red[w][2]=f; red[w][3]=tr; }
  __syncthreads();
  if (tid == 0){
    double KL=0, MD=0, F=0, TR=0;
    for (int ww = 0; ww < 16; ++ww){ KL+=red[ww][0]; MD+=red[ww][1]; F+=red[ww][2]; TR+=red[ww][3]; }
    long msum = 0;
    for (int b = 0; b < 8; ++b){ int v = lengths[b] / STRD; if (v > T_N) v = T_N; msum += v; }
    double inv = 1.0 / (double)msum;
    double total = F*inv + TR*inv + KL*inv + 0.2 * MD / ((double)B_N * T_N * D_N);
    out[0] = (float)total;
  }
}

extern "C" void kernel_launch(void* const* d_in, const int* in_sizes, int n_in,
                              void* d_out, int out_size, void* d_ws, size_t ws_size,
                              hipStream_t stream)
{
  const float* s  = (const float*)d_in[0];
  const float* t  = (const float*)d_in[1];
  // d_in[2] = teacher_codes: unused by the reference computation
  const float* cb = (const float*)d_in[3];
  const int* lengths = (const int*)d_in[4];

  char* ws = (char*)d_ws;
  float* x2s    = (float*)(ws + X2S_OFF);
  float* c2     = (float*)(ws + C2_OFF);
  float* featP  = (float*)(ws + FEATP_OFF);
  float* tripP  = (float*)(ws + TRIPP_OFF);
  float* stateP = (float*)(ws + STATEP_OFF);
  u16* sbf  = (u16*)(ws + SBF_OFF);
  u16* tbf  = (u16*)(ws + TBF_OFF);
  u16* cbbf = (u16*)(ws + CBBF_OFF);

  prep_kernel<<<407, 256, 0, stream>>>(s, t, cb, lengths, sbf, tbf, cbbf,
                                       x2s, c2, featP, tripP);
  main_kl_kernel<<<3000, 256, 0, stream>>>(sbf, tbf, cbbf, c2, stateP);
  tail_kernel<<<1, 1024, 0, stream>>>(stateP, x2s, featP, tripP, lengths, (float*)d_out);
}

// Round 15
// 234.957 us; speedup vs baseline: 1.1636x; 1.1636x over previous
//
#include <hip/hip_runtime.h>

typedef unsigned short u16;
typedef unsigned int   u32;
typedef float  f32x16 __attribute__((ext_vector_type(16)));
typedef __bf16 bf16x8 __attribute__((ext_vector_type(8)));

#define B_N   8
#define T_N   1500
#define D_N   512
#define K_N   4096
#define NTOK  12000
#define STRD  320

// ---- workspace byte offsets (~29.8 MB total) ----
#define X2S_OFF     0u                      // 12000 f
#define C2_OFF      49152u                  // 4096 f
#define FEATP_OFF   65536u                  // 375 f
#define TRIPP_OFF   67584u                  // 375 f
#define STATEP_OFF  69632u                  // 5*4*12000 f
#define SBF_OFF     1048576u                // 375 tiles * 32KB
#define TBF_OFF     (1048576u + 12288000u)
#define CBBF_OFF    (1048576u + 24576000u)  // 4 MB

#define ST_S1  12000                        // stateP ch stride (floats)
#define ST_SQ  48000                        // stateP quantity stride (floats)

// ---- global bf16 layouts, 16B chunks of 8 consecutive k ----
// sbf/tbf: chunk16 = (tt*32 + ks)*64 + kh*32 + sp  (token=tt*32+sp, k=ks*16+kh*8+j)
// cbbf: region r = ch*64 + cg*16 + kc (16KB = 8192 u16); within (u16):
//       off = ctg*1024 + ks2*512 + kh*256 + sp*8
//       (code = ch*1024+cg*256+ctg*32+sp, k = kc*32+ks2*16+kh*8+j)

__device__ __forceinline__ u16 f2bf(float x){
  u32 u = __float_as_uint(x);
  u32 r = (u + 0x7fffu + ((u >> 16) & 1u)) >> 16;   // RNE
  return (u16)r;
}

__device__ __forceinline__ void gl_lds16(const void* g, void* l){
  __builtin_amdgcn_global_load_lds(
      (__attribute__((address_space(1))) void*)(g),
      (__attribute__((address_space(3))) void*)(l),
      16, 0, 0);
}

__device__ __forceinline__ void merge_state(float& m, float& Z, float om, float oZ){
  float nm = fmaxf(m, om);
  Z = Z*__expf(m - nm) + oZ*__expf(om - nm);
  m = nm;
}
__device__ __forceinline__ void merge_stateT(float& m, float& Z, float& A,
                                             float om, float oZ, float oA){
  float nm = fmaxf(m, om);
  float e0 = __expf(m - nm), e1 = __expf(om - nm);
  Z = Z*e0 + oZ*e1; A = A*e0 + oA*e1; m = nm;
}

// ============ prep: blocks 0..374 tokens; 375..406 codebook ============
__global__ __launch_bounds__(256) void prep_kernel(
    const float* __restrict__ s, const float* __restrict__ t,
    const float* __restrict__ cb, const int* __restrict__ lengths,
    u16* __restrict__ sbf, u16* __restrict__ tbf, u16* __restrict__ cbbf,
    float* __restrict__ x2s, float* __restrict__ c2,
    float* __restrict__ featP, float* __restrict__ tripP)
{
  const int tid = threadIdx.x;
  const int w = tid >> 6, lane = tid & 63;
  __shared__ float sred[3][32];

  if (blockIdx.x < 375){
    const int tt = blockIdx.x;
    const int t8 = lane >> 3, kpart = lane & 7;
    const int tokL = w*8 + t8;                  // 0..31
    const int n = tt*32 + tokL;
    const int b = n / T_N, tok = n - b*T_N;
    const int nr = ((b+7)&7)*T_N + tok;         // roll(teacher,+1,axis=0)
    const float* srow = s + (size_t)n  * D_N;
    const float* trow = t + (size_t)n  * D_N;
    const float* rrow = t + (size_t)nr * D_N;

    float x2 = 0.f, sd2 = 0.f, nd2 = 0.f;
    uint4 sbq[8], tbq[8];
#pragma unroll
    for (int q = 0; q < 8; ++q){
      const int kl = q*64 + kpart*8;
      float4 a0 = *(const float4*)(srow + kl), a1 = *(const float4*)(srow + kl + 4);
      float4 b0 = *(const float4*)(trow + kl), b1 = *(const float4*)(trow + kl + 4);
      float4 r0 = *(const float4*)(rrow + kl), r1 = *(const float4*)(rrow + kl + 4);
      float sv[8] = {a0.x,a0.y,a0.z,a0.w,a1.x,a1.y,a1.z,a1.w};
      float tv[8] = {b0.x,b0.y,b0.z,b0.w,b1.x,b1.y,b1.z,b1.w};
      float rv[8] = {r0.x,r0.y,r0.z,r0.w,r1.x,r1.y,r1.z,r1.w};
      u16 sb[8], tb[8];
#pragma unroll
      for (int i = 0; i < 8; ++i){
        float d = sv[i] - tv[i]; sd2 += d*d;
        x2 += sv[i]*sv[i];
        float e = sv[i] - rv[i]; nd2 += e*e;
        sb[i] = f2bf(sv[i]); tb[i] = f2bf(tv[i]);
      }
      sbq[q].x = (u32)sb[0] | ((u32)sb[1]<<16); sbq[q].y = (u32)sb[2] | ((u32)sb[3]<<16);
      sbq[q].z = (u32)sb[4] | ((u32)sb[5]<<16); sbq[q].w = (u32)sb[6] | ((u32)sb[7]<<16);
      tbq[q].x = (u32)tb[0] | ((u32)tb[1]<<16); tbq[q].y = (u32)tb[2] | ((u32)tb[3]<<16);
      tbq[q].z = (u32)tb[4] | ((u32)tb[5]<<16); tbq[q].w = (u32)tb[6] | ((u32)tb[7]<<16);
    }
#pragma unroll
    for (int q = 0; q < 8; ++q){
      const int ks = q*4 + (kpart >> 1), kh = kpart & 1;
      const size_t chunk = ((size_t)tt*32 + ks)*64 + kh*32 + tokL;
      ((uint4*)sbf)[chunk] = sbq[q];
      ((uint4*)tbf)[chunk] = tbq[q];
    }
#pragma unroll
    for (int mm = 1; mm < 8; mm <<= 1){
      x2  += __shfl_xor(x2,  mm);
      sd2 += __shfl_xor(sd2, mm);
      nd2 += __shfl_xor(nd2, mm);
    }
    if (kpart == 0){ sred[0][tokL] = x2; sred[1][tokL] = sd2; sred[2][tokL] = nd2; }
    __syncthreads();
    if (tid < 32){
      float X2 = sred[0][tid], SD = sred[1][tid], ND = sred[2][tid];
      int n2 = tt*32 + tid, b2 = n2 / T_N, tk2 = n2 - b2*T_N;
      x2s[n2] = X2;
      int valid = lengths[b2] / STRD; if (valid > T_N) valid = T_N;
      float mf = (tk2 < valid) ? 1.f : 0.f;
      float fp = mf * SD * (1.f/512.f);
      float tp = mf * fmaxf(sqrtf(SD) - sqrtf(ND) + 0.2f, 0.f);
#pragma unroll
      for (int mm = 1; mm < 32; mm <<= 1){ fp += __shfl_xor(fp, mm); tp += __shfl_xor(tp, mm); }
      if (tid == 0){ featP[tt] = fp; tripP[tt] = tp; }
    }
  } else {
    const int idx = blockIdx.x - 375;
    const int ctile = idx*4 + w;                // 0..127
    const int kh = lane >> 5, sp = lane & 31;
    const int ch = ctile >> 5, cg = (ctile >> 3) & 3, ctg = ctile & 7;
    const int code = ctile*32 + sp;
    const float* crow = cb + (size_t)code * D_N;

    float s2 = 0.f;
#pragma unroll
    for (int stp = 0; stp < 32; ++stp){
      const int kc = stp >> 1, ks2 = stp & 1;
      const int k0 = stp*16 + kh*8;
      float4 c0 = *(const float4*)(crow + k0), c1 = *(const float4*)(crow + k0 + 4);
      float cv[8] = {c0.x,c0.y,c0.z,c0.w,c1.x,c1.y,c1.z,c1.w};
      u16 cbv[8];
#pragma unroll
      for (int i = 0; i < 8; ++i){ s2 += cv[i]*cv[i]; cbv[i] = f2bf(cv[i]); }
      uint4 pk;
      pk.x = (u32)cbv[0] | ((u32)cbv[1]<<16); pk.y = (u32)cbv[2] | ((u32)cbv[3]<<16);
      pk.z = (u32)cbv[4] | ((u32)cbv[5]<<16); pk.w = (u32)cbv[6] | ((u32)cbv[7]<<16);
      const size_t off = ((size_t)(ch*64 + cg*16 + kc))*8192 + ctg*1024 + ks2*512 + lane*8;
      *(uint4*)(cbbf + off) = pk;
    }
    s2 += __shfl_xor(s2, 32);
    if (lane < 32) c2[ctile*32 + lane] = s2;
  }
}

// ============ main: 32 tok x 1024 codes; A fully LDS-resident, barrier-free K-loop ============
// grid 1500 = 375 token-tiles x 4 code-quarters. 64 chunks of 256 codes x 32 k.
// A (s+t, 64 KB) staged ONCE by DMA; B codebook frags global->VGPR with 1-chunk
// prefetch (fine-grained vmcnt, no barrier drain). LDS 64 KB -> 2 blocks/CU.
__global__ __launch_bounds__(256, 2) void main_kl_kernel(
    const u16* __restrict__ sbf, const u16* __restrict__ tbf,
    const u16* __restrict__ cbbf, const float* __restrict__ c2,
    float* __restrict__ stateP)
{
  __shared__ u16 Ab[32768];                     // 64 KB: [0..16K)=s, [16K..32K)=t

  const int tid = threadIdx.x;
  const int w = tid >> 6, lane = tid & 63;
  const int kh = lane >> 5;
  const int blk = blockIdx.x;
  const int tt = blk % 375, ch = blk / 375;

  const u16* cbB = cbbf + (size_t)ch * 524288;  // 64 regions x 8192 u16
  const u16* sA = sbf + (size_t)tt * 16384;
  const u16* tA = tbf + (size_t)tt * 16384;

  // ---- stage A once: 64 KB contiguous copy (fragment order == global order) ----
#pragma unroll
  for (int r = 0; r < 8; ++r){
    const int off = (r*256 + tid)*8;
    gl_lds16(sA + off, &Ab[off]);
    gl_lds16(tA + off, &Ab[16384 + off]);
  }

  // B frags chunk 0 (region 0)
  bf16x8 b00, b01, b10, b11;                    // [ct][ks]
  {
    const u16* rg = cbB;
    b00 = *(const bf16x8*)(rg + (w*2+0)*1024 +       lane*8);
    b01 = *(const bf16x8*)(rg + (w*2+0)*1024 + 512 + lane*8);
    b10 = *(const bf16x8*)(rg + (w*2+1)*1024 +       lane*8);
    b11 = *(const bf16x8*)(rg + (w*2+1)*1024 + 512 + lane*8);
  }

  __syncthreads();                              // A staged (the ONLY pre-loop barrier)

  float mS = -3e38f, zS = 0.f, mT = -3e38f, zT = 0.f, aa = 0.f;
  f32x16 a0s, a0t, a1s, a1t;                    // [ct][mat]

  for (int c = 0; c < 64; ++c){
    const int kc = c & 15;
    if (kc == 0){
#pragma unroll
      for (int i = 0; i < 16; ++i){ a0s[i]=0.f; a0t[i]=0.f; a1s[i]=0.f; a1t[i]=0.f; }
    }
    // prefetch next chunk's B frags (retires via fine-grained vmcnt, no barrier)
    bf16x8 n00 = b00, n01 = b01, n10 = b10, n11 = b11;
    if (c < 63){
      const u16* rg = cbB + (size_t)(c+1)*8192;
      n00 = *(const bf16x8*)(rg + (w*2+0)*1024 +       lane*8);
      n01 = *(const bf16x8*)(rg + (w*2+0)*1024 + 512 + lane*8);
      n10 = *(const bf16x8*)(rg + (w*2+1)*1024 +       lane*8);
      n11 = *(const bf16x8*)(rg + (w*2+1)*1024 + 512 + lane*8);
    }

    // A frags from LDS (depend only on kc)
    const u16* ap = &Ab[kc*1024 + lane*8];
    bf16x8 as0 = *(const bf16x8*)(ap);
    bf16x8 as1 = *(const bf16x8*)(ap + 512);
    bf16x8 at0 = *(const bf16x8*)(ap + 16384);
    bf16x8 at1 = *(const bf16x8*)(ap + 16896);

    a0s = __builtin_amdgcn_mfma_f32_32x32x16_bf16(b00, as0, a0s, 0, 0, 0);
    a0t = __builtin_amdgcn_mfma_f32_32x32x16_bf16(b00, at0, a0t, 0, 0, 0);
    a1s = __builtin_amdgcn_mfma_f32_32x32x16_bf16(b10, as0, a1s, 0, 0, 0);
    a1t = __builtin_amdgcn_mfma_f32_32x32x16_bf16(b10, at0, a1t, 0, 0, 0);
    a0s = __builtin_amdgcn_mfma_f32_32x32x16_bf16(b01, as1, a0s, 0, 0, 0);
    a0t = __builtin_amdgcn_mfma_f32_32x32x16_bf16(b01, at1, a0t, 0, 0, 0);
    a1s = __builtin_amdgcn_mfma_f32_32x32x16_bf16(b11, as1, a1s, 0, 0, 0);
    a1t = __builtin_amdgcn_mfma_f32_32x32x16_bf16(b11, at1, a1t, 0, 0, 0);
    b00 = n00; b01 = n01; b10 = n10; b11 = n11;

    if (kc == 15){
      const int cg = c >> 4;
#pragma unroll
      for (int ct = 0; ct < 2; ++ct){
        const f32x16& vS = ct ? a1s : a0s;
        const f32x16& vT = ct ? a1t : a0t;
        const int ctg = w*2 + ct;
        const float* c2b = c2 + ch*1024 + cg*256 + ctg*32 + kh*4;
        float4 g0 = *(const float4*)(c2b);
        float4 g1 = *(const float4*)(c2b + 8);
        float4 g2 = *(const float4*)(c2b + 16);
        float4 g3 = *(const float4*)(c2b + 24);
        float c2v[16] = {g0.x,g0.y,g0.z,g0.w, g1.x,g1.y,g1.z,g1.w,
                         g2.x,g2.y,g2.z,g2.w, g3.x,g3.y,g3.z,g3.w};
        // pass 1: tile maxes
        float ms_t = -3e38f, mt_t = -3e38f;
#pragma unroll
        for (int i = 0; i < 16; ++i){
          ms_t = fmaxf(ms_t, 2.0f*vS[i] - c2v[i]);
          mt_t = fmaxf(mt_t, 2.0f*vT[i] - c2v[i]);
        }
        float nmS = fmaxf(mS, ms_t), nmT = fmaxf(mT, mt_t);
        float esS = __expf(mS - nmS), esT = __expf(mT - nmT);
        zS *= esS; zT *= esT; aa *= esT;
        // pass 2: recompute logits, accumulate
#pragma unroll
        for (int i = 0; i < 16; ++i){
          float sl = 2.0f*vS[i] - c2v[i];
          float tl = 2.0f*vT[i] - c2v[i];
          zS += __expf(sl - nmS);
          float e = __expf(tl - nmT);
          zT += e; aa += e*(tl - sl);
        }
        mS = nmS; mT = nmT;
      }
    }
  }

  // merge the two code-row halves (xor 32: same token, disjoint code rows)
  {
    float om = __shfl_xor(mS, 32), oZ = __shfl_xor(zS, 32);
    merge_state(mS, zS, om, oZ);
    float omt = __shfl_xor(mT, 32), ozt = __shfl_xor(zT, 32), oA = __shfl_xor(aa, 32);
    merge_stateT(mT, zT, aa, omt, ozt, oA);
  }
  __syncthreads();                              // Ab dead; reuse as merge buffer
  float* wst = (float*)&Ab[0];                  // [4][32][5] = 2.5 KB
  if (lane < 32){
    float* pw = wst + (w*32 + lane)*5;
    pw[0] = mS; pw[1] = zS; pw[2] = mT; pw[3] = zT; pw[4] = aa;
  }
  __syncthreads();
  if (tid < 32){
    const float* p0 = wst + tid*5;
    float m_s = p0[0], z_s = p0[1], m_t = p0[2], z_t = p0[3], a = p0[4];
#pragma unroll
    for (int ww = 1; ww < 4; ++ww){
      const float* pw = wst + (ww*32 + tid)*5;
      merge_state(m_s, z_s, pw[0], pw[1]);
      merge_stateT(m_t, z_t, a, pw[2], pw[3], pw[4]);
    }
    const int n = tt*32 + tid;
    stateP[0*ST_SQ + ch*ST_S1 + n] = m_s;
    stateP[1*ST_SQ + ch*ST_S1 + n] = z_s;
    stateP[2*ST_SQ + ch*ST_S1 + n] = m_t;
    stateP[3*ST_SQ + ch*ST_S1 + n] = z_t;
    stateP[4*ST_SQ + ch*ST_S1 + n] = a;
  }
}

// ============ tail: merge 4 code-quarters per token; KL/min-dist; reduce ============
__global__ __launch_bounds__(1024) void tail_kernel(
    const float* __restrict__ stateP, const float* __restrict__ x2s,
    const float* __restrict__ featP, const float* __restrict__ tripP,
    const int* __restrict__ lengths, float* __restrict__ out)
{
  const int tid = threadIdx.x;
  double kl_s = 0.0, md_s = 0.0, f = 0.0, tr = 0.0;
  for (int n = tid; n < NTOK; n += 1024){
    float m_s = stateP[0*ST_SQ + n], z_s = stateP[1*ST_SQ + n];
    float m_t = stateP[2*ST_SQ + n], z_t = stateP[3*ST_SQ + n], a = stateP[4*ST_SQ + n];
#pragma unroll
    for (int chh = 1; chh < 4; ++chh){
      merge_state(m_s, z_s, stateP[0*ST_SQ + chh*ST_S1 + n], stateP[1*ST_SQ + chh*ST_S1 + n]);
      merge_stateT(m_t, z_t, a, stateP[2*ST_SQ + chh*ST_S1 + n],
                   stateP[3*ST_SQ + chh*ST_S1 + n], stateP[4*ST_SQ + chh*ST_S1 + n]);
    }
    float klv = a / z_t - (m_t + __logf(z_t)) + (m_s + __logf(z_s));
    int b = n / T_N, tk = n - b*T_N;
    int valid = lengths[b] / STRD; if (valid > T_N) valid = T_N;
    if (tk < valid) kl_s += (double)klv;
    md_s += (double)fmaxf(x2s[n] - m_s, 0.f);
  }
  for (int i = tid; i < 375; i += 1024){ f += (double)featP[i]; tr += (double)tripP[i]; }
#pragma unroll
  for (int mm = 1; mm < 64; mm <<= 1){
    kl_s += __shfl_xor(kl_s, mm); md_s += __shfl_xor(md_s, mm);
    f    += __shfl_xor(f,    mm); tr   += __shfl_xor(tr,   mm);
  }
  __shared__ double red[16][4];
  const int w = tid >> 6, lane = tid & 63;
  if (lane == 0){ red[w][0]=kl_s; red[w][1]=md_s; red[w][2]=f; red[w][3]=tr; }
  __syncthreads();
  if (tid == 0){
    double KL=0, MD=0, F=0, TR=0;
    for (int ww = 0; ww < 16; ++ww){ KL+=red[ww][0]; MD+=red[ww][1]; F+=red[ww][2]; TR+=red[ww][3]; }
    long msum = 0;
    for (int b = 0; b < 8; ++b){ int v = lengths[b] / STRD; if (v > T_N) v = T_N; msum += v; }
    double inv = 1.0 / (double)msum;
    double total = F*inv + TR*inv + KL*inv + 0.2 * MD / ((double)B_N * T_N * D_N);
    out[0] = (float)total;
  }
}

extern "C" void kernel_launch(void* const* d_in, const int* in_sizes, int n_in,
                              void* d_out, int out_size, void* d_ws, size_t ws_size,
                              hipStream_t stream)
{
  const float* s  = (const float*)d_in[0];
  const float* t  = (const float*)d_in[1];
  // d_in[2] = teacher_codes: unused by the reference computation
  const float* cb = (const float*)d_in[3];
  const int* lengths = (const int*)d_in[4];

  char* ws = (char*)d_ws;
  float* x2s    = (float*)(ws + X2S_OFF);
  float* c2     = (float*)(ws + C2_OFF);
  float* featP  = (float*)(ws + FEATP_OFF);
  float* tripP  = (float*)(ws + TRIPP_OFF);
  float* stateP = (float*)(ws + STATEP_OFF);
  u16* sbf  = (u16*)(ws + SBF_OFF);
  u16* tbf  = (u16*)(ws + TBF_OFF);
  u16* cbbf = (u16*)(ws + CBBF_OFF);

  prep_kernel<<<407, 256, 0, stream>>>(s, t, cb, lengths, sbf, tbf, cbbf,
                                       x2s, c2, featP, tripP);
  main_kl_kernel<<<1500, 256, 0, stream>>>(sbf, tbf, cbbf, c2, stateP);
  tail_kernel<<<1, 1024, 0, stream>>>(stateP, x2s, featP, tripP, lengths, (float*)d_out);
}